// Round 3
// baseline (829.489 us; speedup 1.0000x reference)
//
#include <hip/hip_runtime.h>
#include <math.h>

#define N_NODES 100000
#define N_EDGES 3200000
#define BSHIFT 8
#define NPB 256                 // nodes per bucket = 1<<BSHIFT
#define BMASK (NPB - 1)
#define NB 391                  // ceil(N_NODES / NPB)
#define CAP 10240               // bucket capacity (E[edges/bucket]=8184, +22 sigma)

// ---------------------------------------------------------------------------
// fc1: h1 = relu(x @ W1 + b1)   x:[N,512] f32, W1:[512,16], h1:[N,16]
// Wave handles 4 rows; W1 transposed in LDS; pair-merge butterfly reduce.
// ---------------------------------------------------------------------------
__global__ __launch_bounds__(256) void fc1_kernel(
    const float* __restrict__ x, const float* __restrict__ w,
    const float* __restrict__ b, float* __restrict__ h1) {
  __shared__ float wt[16][512];
  for (int idx = threadIdx.x; idx < 512 * 16; idx += 256) {
    int e = idx >> 4, o = idx & 15;
    wt[o][e] = w[idx];
  }
  __syncthreads();

  const int lane = threadIdx.x & 63;
  const int wid = blockIdx.x * 4 + (threadIdx.x >> 6);
  const int waves_total = gridDim.x * 4;
  const float bl = b[lane & 15];
  const int ngroups = N_NODES / 4;  // 25000

  for (int g = wid; g < ngroups; g += waves_total) {
    const int r0 = g * 4;
    float4 xa[4][2];
#pragma unroll
    for (int r = 0; r < 4; ++r) {
      const float4* xp = (const float4*)(x + (size_t)(r0 + r) * 512 + lane * 4);
      xa[r][0] = xp[0];
      xa[r][1] = xp[64];
    }
    float acc[4][16];
#pragma unroll
    for (int r = 0; r < 4; ++r)
#pragma unroll
      for (int o = 0; o < 16; ++o) acc[r][o] = 0.f;

#pragma unroll
    for (int o = 0; o < 16; ++o) {
      const float4 w0 = *(const float4*)&wt[o][lane * 4];
      const float4 w1 = *(const float4*)&wt[o][256 + lane * 4];
#pragma unroll
      for (int r = 0; r < 4; ++r) {
        acc[r][o] += xa[r][0].x * w0.x + xa[r][0].y * w0.y +
                     xa[r][0].z * w0.z + xa[r][0].w * w0.w +
                     xa[r][1].x * w1.x + xa[r][1].y * w1.y +
                     xa[r][1].z * w1.z + xa[r][1].w * w1.w;
      }
    }

    const bool b0 = lane & 1, b1 = lane & 2, b2 = lane & 4, b3 = lane & 8;
#pragma unroll
    for (int r = 0; r < 4; ++r) {
      float v8[8];
#pragma unroll
      for (int j = 0; j < 8; ++j) {
        float keep = b0 ? acc[r][2 * j + 1] : acc[r][2 * j];
        float give = b0 ? acc[r][2 * j] : acc[r][2 * j + 1];
        v8[j] = keep + __shfl_xor(give, 1, 64);
      }
      float v4[4];
#pragma unroll
      for (int j = 0; j < 4; ++j) {
        float keep = b1 ? v8[2 * j + 1] : v8[2 * j];
        float give = b1 ? v8[2 * j] : v8[2 * j + 1];
        v4[j] = keep + __shfl_xor(give, 2, 64);
      }
      float v2[2];
#pragma unroll
      for (int j = 0; j < 2; ++j) {
        float keep = b2 ? v4[2 * j + 1] : v4[2 * j];
        float give = b2 ? v4[2 * j] : v4[2 * j + 1];
        v2[j] = keep + __shfl_xor(give, 4, 64);
      }
      float keep = b3 ? v2[1] : v2[0];
      float give = b3 ? v2[0] : v2[1];
      float v1 = keep + __shfl_xor(give, 8, 64);
      v1 += __shfl_xor(v1, 16, 64);
      v1 += __shfl_xor(v1, 32, 64);
      if (lane < 16) {
        h1[(size_t)(r0 + r) * 16 + lane] = fmaxf(v1 + bl, 0.f);
      }
    }
  }
}

// ---------------------------------------------------------------------------
// Bucket scatter: edges grouped by dst>>8 into staging, packed (src<<8)|dstlow.
// Per block: LDS histogram -> one global atomic per touched bucket -> scatter.
// Writes per (block,bucket) are contiguous runs (~full cache lines).
// ---------------------------------------------------------------------------
__global__ __launch_bounds__(256) void stage_kernel(
    const int* __restrict__ src, const int* __restrict__ dst,
    int* __restrict__ gcur, int* __restrict__ staged) {
  __shared__ int hist[NB];
  __shared__ int base[NB];
  const int tid = threadIdx.x;
  for (int i = tid; i < NB; i += 256) hist[i] = 0;
  __syncthreads();

  const int per = (N_EDGES + gridDim.x - 1) / gridDim.x;
  const int e0 = blockIdx.x * per;
  const int e1 = min(e0 + per, N_EDGES);

  for (int e = e0 + tid; e < e1; e += 256) {
    atomicAdd(&hist[dst[e] >> BSHIFT], 1);
  }
  __syncthreads();
  for (int bkt = tid; bkt < NB; bkt += 256) {
    int h = hist[bkt];
    base[bkt] = (h > 0) ? atomicAdd(&gcur[bkt], h) : 0;
    hist[bkt] = 0;  // reuse as local cursor
  }
  __syncthreads();
  for (int e = e0 + tid; e < e1; e += 256) {
    int d = dst[e];
    int s = src[e];
    int bkt = d >> BSHIFT;
    int pos = base[bkt] + atomicAdd(&hist[bkt], 1);
    if (pos < CAP) staged[bkt * CAP + pos] = (s << 8) | (d & BMASK);
  }
}

// ---------------------------------------------------------------------------
// conv1 (16 -> 32): one block per bucket. Edge phase: 4 threads/edge gather
// h1[src] (coalesced float4) and ds_add_f32 into LDS agg[256][17]. Node
// phase: thread-per-node transform; epilogue also emits t2 = h2row @ c2llw
// (pre-transform for conv2, 32->16, mean is linear so agg(t2) == agg(h2)@llw).
// ---------------------------------------------------------------------------
__global__ __launch_bounds__(512) void conv1_kernel(
    const float* __restrict__ h1, const int* __restrict__ staged,
    const int* __restrict__ gcur, const float* __restrict__ llw,
    const float* __restrict__ llb, const float* __restrict__ lrw,
    const float* __restrict__ c2llw, float* __restrict__ h2,
    float* __restrict__ t2) {
  __shared__ float agg[NPB][17];
  __shared__ int deg[NPB];
  __shared__ float wl[512], wr[512], w2[512];
  __shared__ float bb[32];
  const int tid = threadIdx.x;
  wl[tid] = llw[tid];
  wr[tid] = lrw[tid];
  w2[tid] = c2llw[tid];
  if (tid < 32) bb[tid] = llb[tid];
  for (int i = tid; i < NPB * 17; i += 512) ((float*)agg)[i] = 0.f;
  for (int i = tid; i < NPB; i += 512) deg[i] = 0;
  __syncthreads();

  const int bkt = blockIdx.x;
  const int nE = min(gcur[bkt], CAP);
  const int ew = tid >> 2, t = tid & 3;
  const int sbase = bkt * CAP;

  for (int e = ew; e < nE; e += 128) {
    int u = staged[sbase + e];
    int s = u >> 8;
    int dl = u & BMASK;
    float4 v = *(const float4*)(h1 + (size_t)s * 16 + t * 4);
    atomicAdd(&agg[dl][t * 4 + 0], v.x);
    atomicAdd(&agg[dl][t * 4 + 1], v.y);
    atomicAdd(&agg[dl][t * 4 + 2], v.z);
    atomicAdd(&agg[dl][t * 4 + 3], v.w);
    if (t == 0) atomicAdd(&deg[dl], 1);
  }
  __syncthreads();

  if (tid < NPB) {
    const int g = bkt * NPB + tid;
    if (g < N_NODES) {
      const int d = deg[tid];
      const float inv = 1.f / (float)(d > 0 ? d : 1);
      float mk[16], sk[16];
#pragma unroll
      for (int k = 0; k < 16; ++k) mk[k] = agg[tid][k] * inv;
      const float4* sp = (const float4*)(h1 + (size_t)g * 16);
#pragma unroll
      for (int q = 0; q < 4; ++q) {
        float4 a = sp[q];
        sk[4 * q] = a.x; sk[4 * q + 1] = a.y;
        sk[4 * q + 2] = a.z; sk[4 * q + 3] = a.w;
      }
      float o[32];
#pragma unroll
      for (int j = 0; j < 32; ++j) {
        float v = bb[j];
#pragma unroll
        for (int k = 0; k < 16; ++k)
          v += mk[k] * wl[k * 32 + j] + sk[k] * wr[k * 32 + j];
        o[j] = fmaxf(v, 0.f);
      }
      float4* hp = (float4*)(h2 + (size_t)g * 32);
#pragma unroll
      for (int q = 0; q < 8; ++q)
        hp[q] = make_float4(o[4 * q], o[4 * q + 1], o[4 * q + 2], o[4 * q + 3]);
      float tt[16];
#pragma unroll
      for (int j = 0; j < 16; ++j) {
        float v = 0.f;
#pragma unroll
        for (int k = 0; k < 32; ++k) v += o[k] * w2[k * 16 + j];
        tt[j] = v;
      }
      float4* tp = (float4*)(t2 + (size_t)g * 16);
#pragma unroll
      for (int q = 0; q < 4; ++q)
        tp[q] = make_float4(tt[4 * q], tt[4 * q + 1], tt[4 * q + 2], tt[4 * q + 3]);
    }
  }
}

// ---------------------------------------------------------------------------
// conv2 (32 -> 16, pre-transformed) + fc2 + head -> d_out.
// Edge phase aggregates t2 (16 dims). Node phase: f = relu(mean_t2 + llb +
// h2row @ lrw); head = sigmoid/relu mix.
// ---------------------------------------------------------------------------
__global__ __launch_bounds__(512) void conv2_kernel(
    const float* __restrict__ t2, const float* __restrict__ h2,
    const int* __restrict__ staged, const int* __restrict__ gcur,
    const float* __restrict__ llb, const float* __restrict__ lrw,
    const float* __restrict__ fc2w, const float* __restrict__ fc2b,
    float* __restrict__ out) {
  __shared__ float agg[NPB][17];
  __shared__ int deg[NPB];
  __shared__ float wr[512];
  __shared__ float bb[16];
  __shared__ float w2[48];
  __shared__ float b2[3];
  const int tid = threadIdx.x;
  wr[tid] = lrw[tid];
  if (tid < 16) bb[tid] = llb[tid];
  else if (tid >= 64 && tid < 112) w2[tid - 64] = fc2w[tid - 64];
  else if (tid >= 128 && tid < 131) b2[tid - 128] = fc2b[tid - 128];
  for (int i = tid; i < NPB * 17; i += 512) ((float*)agg)[i] = 0.f;
  for (int i = tid; i < NPB; i += 512) deg[i] = 0;
  __syncthreads();

  const int bkt = blockIdx.x;
  const int nE = min(gcur[bkt], CAP);
  const int ew = tid >> 2, t = tid & 3;
  const int sbase = bkt * CAP;

  for (int e = ew; e < nE; e += 128) {
    int u = staged[sbase + e];
    int s = u >> 8;
    int dl = u & BMASK;
    float4 v = *(const float4*)(t2 + (size_t)s * 16 + t * 4);
    atomicAdd(&agg[dl][t * 4 + 0], v.x);
    atomicAdd(&agg[dl][t * 4 + 1], v.y);
    atomicAdd(&agg[dl][t * 4 + 2], v.z);
    atomicAdd(&agg[dl][t * 4 + 3], v.w);
    if (t == 0) atomicAdd(&deg[dl], 1);
  }
  __syncthreads();

  if (tid < NPB) {
    const int g = bkt * NPB + tid;
    if (g < N_NODES) {
      const int d = deg[tid];
      const float inv = 1.f / (float)(d > 0 ? d : 1);
      float self[32];
      const float4* sp = (const float4*)(h2 + (size_t)g * 32);
#pragma unroll
      for (int q = 0; q < 8; ++q) {
        float4 a = sp[q];
        self[4 * q] = a.x; self[4 * q + 1] = a.y;
        self[4 * q + 2] = a.z; self[4 * q + 3] = a.w;
      }
      float f[16];
#pragma unroll
      for (int j = 0; j < 16; ++j) {
        float v = agg[tid][j] * inv + bb[j];
#pragma unroll
        for (int k = 0; k < 32; ++k) v += self[k] * wr[k * 16 + j];
        f[j] = fmaxf(v, 0.f);
      }
      float v0 = b2[0], v1 = b2[1], v2 = b2[2];
#pragma unroll
      for (int k = 0; k < 16; ++k) {
        v0 += f[k] * w2[k * 3 + 0];
        v1 += f[k] * w2[k * 3 + 1];
        v2 += f[k] * w2[k * 3 + 2];
      }
      float gsi = 1.f / (1.f + expf(-v1));
      float mxi = 1.f / (1.f + expf(-v2));
      float fsi = fmaxf(v0, 0.f) + gsi;
      out[(size_t)g * 3 + 0] = fsi;
      out[(size_t)g * 3 + 1] = gsi;
      out[(size_t)g * 3 + 2] = mxi;
    }
  }
}

extern "C" void kernel_launch(void* const* d_in, const int* in_sizes, int n_in,
                              void* d_out, int out_size, void* d_ws, size_t ws_size,
                              hipStream_t stream) {
  const float* x = (const float*)d_in[0];
  const int* ei = (const int*)d_in[1];
  const float* fc1w = (const float*)d_in[2];
  const float* fc1b = (const float*)d_in[3];
  const float* c1llw = (const float*)d_in[4];
  const float* c1llb = (const float*)d_in[5];
  const float* c1lrw = (const float*)d_in[6];
  const float* c2llw = (const float*)d_in[7];
  const float* c2llb = (const float*)d_in[8];
  const float* c2lrw = (const float*)d_in[9];
  const float* fc2w = (const float*)d_in[10];
  const float* fc2b = (const float*)d_in[11];
  float* outp = (float*)d_out;
  const int* src = ei;
  const int* dst = ei + N_EDGES;

  char* ws = (char*)d_ws;
  float* h1 = (float*)ws;    ws += (size_t)N_NODES * 16 * 4;
  float* h2 = (float*)ws;    ws += (size_t)N_NODES * 32 * 4;
  float* t2 = (float*)ws;    ws += (size_t)N_NODES * 16 * 4;
  int* staged = (int*)ws;    ws += (size_t)NB * CAP * 4;
  int* gcur = (int*)ws;      ws += (size_t)NB * 4;
  (void)ws_size; (void)n_in; (void)in_sizes; (void)out_size;

  hipMemsetAsync(gcur, 0, (size_t)NB * 4, stream);
  fc1_kernel<<<512, 256, 0, stream>>>(x, fc1w, fc1b, h1);
  stage_kernel<<<512, 256, 0, stream>>>(src, dst, gcur, staged);
  conv1_kernel<<<NB, 512, 0, stream>>>(h1, staged, gcur, c1llw, c1llb, c1lrw,
                                       c2llw, h2, t2);
  conv2_kernel<<<NB, 512, 0, stream>>>(t2, h2, staged, gcur, c2llb, c2lrw,
                                       fc2w, fc2b, outp);
}

// Round 4
// 304.752 us; speedup vs baseline: 2.7219x; 2.7219x over previous
//
#include <hip/hip_runtime.h>
#include <math.h>

#define N_NODES 100000
#define N_EDGES 3200000
#define BSHIFT 8
#define NPB 256                 // nodes per bucket = 1<<BSHIFT
#define BMASK (NPB - 1)
#define NB 391                  // ceil(N_NODES / NPB)
#define CAP 10240               // bucket capacity (mean 8192, +22 sigma)

// ---------------------------------------------------------------------------
// fc1: h1 = relu(x @ W1 + b1)   x:[N,512] f32, W1:[512,16], h1:[N,16]
// ---------------------------------------------------------------------------
__global__ __launch_bounds__(256) void fc1_kernel(
    const float* __restrict__ x, const float* __restrict__ w,
    const float* __restrict__ b, float* __restrict__ h1) {
  __shared__ float wt[16][512];
  for (int idx = threadIdx.x; idx < 512 * 16; idx += 256) {
    int e = idx >> 4, o = idx & 15;
    wt[o][e] = w[idx];
  }
  __syncthreads();

  const int lane = threadIdx.x & 63;
  const int wid = blockIdx.x * 4 + (threadIdx.x >> 6);
  const int waves_total = gridDim.x * 4;
  const float bl = b[lane & 15];
  const int ngroups = N_NODES / 4;  // 25000

  for (int g = wid; g < ngroups; g += waves_total) {
    const int r0 = g * 4;
    float4 xa[4][2];
#pragma unroll
    for (int r = 0; r < 4; ++r) {
      const float4* xp = (const float4*)(x + (size_t)(r0 + r) * 512 + lane * 4);
      xa[r][0] = xp[0];
      xa[r][1] = xp[64];
    }
    float acc[4][16];
#pragma unroll
    for (int r = 0; r < 4; ++r)
#pragma unroll
      for (int o = 0; o < 16; ++o) acc[r][o] = 0.f;

#pragma unroll
    for (int o = 0; o < 16; ++o) {
      const float4 w0 = *(const float4*)&wt[o][lane * 4];
      const float4 w1 = *(const float4*)&wt[o][256 + lane * 4];
#pragma unroll
      for (int r = 0; r < 4; ++r) {
        acc[r][o] += xa[r][0].x * w0.x + xa[r][0].y * w0.y +
                     xa[r][0].z * w0.z + xa[r][0].w * w0.w +
                     xa[r][1].x * w1.x + xa[r][1].y * w1.y +
                     xa[r][1].z * w1.z + xa[r][1].w * w1.w;
      }
    }

    const bool b0 = lane & 1, b1 = lane & 2, b2 = lane & 4, b3 = lane & 8;
#pragma unroll
    for (int r = 0; r < 4; ++r) {
      float v8[8];
#pragma unroll
      for (int j = 0; j < 8; ++j) {
        float keep = b0 ? acc[r][2 * j + 1] : acc[r][2 * j];
        float give = b0 ? acc[r][2 * j] : acc[r][2 * j + 1];
        v8[j] = keep + __shfl_xor(give, 1, 64);
      }
      float v4[4];
#pragma unroll
      for (int j = 0; j < 4; ++j) {
        float keep = b1 ? v8[2 * j + 1] : v8[2 * j];
        float give = b1 ? v8[2 * j] : v8[2 * j + 1];
        v4[j] = keep + __shfl_xor(give, 2, 64);
      }
      float v2[2];
#pragma unroll
      for (int j = 0; j < 2; ++j) {
        float keep = b2 ? v4[2 * j + 1] : v4[2 * j];
        float give = b2 ? v4[2 * j] : v4[2 * j + 1];
        v2[j] = keep + __shfl_xor(give, 4, 64);
      }
      float keep = b3 ? v2[1] : v2[0];
      float give = b3 ? v2[0] : v2[1];
      float v1 = keep + __shfl_xor(give, 8, 64);
      v1 += __shfl_xor(v1, 16, 64);
      v1 += __shfl_xor(v1, 32, 64);
      if (lane < 16) {
        h1[(size_t)(r0 + r) * 16 + lane] = fmaxf(v1 + bl, 0.f);
      }
    }
  }
}

// ---------------------------------------------------------------------------
// Bucket scatter: edges grouped by dst>>8, packed (src<<8)|dstlow.
// Per-block LDS histogram -> one global atomic per touched bucket -> scatter
// in contiguous runs (full cache lines).
// ---------------------------------------------------------------------------
__global__ __launch_bounds__(256) void stage_kernel(
    const int* __restrict__ src, const int* __restrict__ dst,
    int* __restrict__ gcur, int* __restrict__ staged) {
  __shared__ int hist[NB];
  __shared__ int base[NB];
  const int tid = threadIdx.x;
  for (int i = tid; i < NB; i += 256) hist[i] = 0;
  __syncthreads();

  const int per = (N_EDGES + gridDim.x - 1) / gridDim.x;
  const int e0 = blockIdx.x * per;
  const int e1 = min(e0 + per, N_EDGES);

  for (int e = e0 + tid; e < e1; e += 256) {
    atomicAdd(&hist[dst[e] >> BSHIFT], 1);
  }
  __syncthreads();
  for (int bkt = tid; bkt < NB; bkt += 256) {
    int h = hist[bkt];
    base[bkt] = (h > 0) ? atomicAdd(&gcur[bkt], h) : 0;
    hist[bkt] = 0;  // reuse as local cursor
  }
  __syncthreads();
  for (int e = e0 + tid; e < e1; e += 256) {
    int d = dst[e];
    int s = src[e];
    int bkt = d >> BSHIFT;
    int pos = base[bkt] + atomicAdd(&hist[bkt], 1);
    if (pos < CAP) staged[bkt * CAP + pos] = (s << 8) | (d & BMASK);
  }
}

// ---------------------------------------------------------------------------
// finalize: per bucket, load staged slice into LDS, histogram local dst,
// block-scan -> per-node offs/cnt, scatter src back IN PLACE node-sorted.
// All writes land in one 40KB window owned by one block.
// ---------------------------------------------------------------------------
__global__ __launch_bounds__(256) void finalize_kernel(
    int* __restrict__ staged, const int* __restrict__ gcur,
    int* __restrict__ offs, int* __restrict__ cnt) {
  __shared__ int ed[CAP];
  __shared__ int lcnt[NPB];
  __shared__ int lofs[NPB];
  __shared__ int sc[256];
  const int bkt = blockIdx.x, tid = threadIdx.x;
  const int nE = min(gcur[bkt], CAP);
  const int base = bkt * CAP;
  for (int e = tid; e < nE; e += 256) ed[e] = staged[base + e];
  lcnt[tid] = 0;
  __syncthreads();
  for (int e = tid; e < nE; e += 256) atomicAdd(&lcnt[ed[e] & BMASK], 1);
  __syncthreads();
  const int v = lcnt[tid];
  sc[tid] = v;
  __syncthreads();
  for (int d = 1; d < 256; d <<= 1) {
    int add = (tid >= d) ? sc[tid - d] : 0;
    __syncthreads();
    sc[tid] += add;
    __syncthreads();
  }
  const int excl = sc[tid] - v;
  lofs[tid] = excl;
  const int g = bkt * NPB + tid;
  if (g < N_NODES) {
    offs[g] = base + excl;
    cnt[g] = v;
  }
  lcnt[tid] = 0;  // reuse as cursor
  __syncthreads();
  for (int e = tid; e < nE; e += 256) {
    int u = ed[e];
    int dl = u & BMASK;
    int pos = lofs[dl] + atomicAdd(&lcnt[dl], 1);
    staged[base + pos] = u >> 8;  // plain src index, node-sorted
  }
}

// ---------------------------------------------------------------------------
// conv1 (16 -> 32): 4 threads/node gather h1[src] (coalesced 64B/edge).
// Partial matmul on k-slice, butterfly over 4 lanes -> full o[32] per lane.
// Epilogue: write h2 and t2 = o @ c2llw (pre-transform for conv2; mean is
// linear so agg(t2) == agg(h2) @ c2llw).
// ---------------------------------------------------------------------------
__global__ __launch_bounds__(256) void conv1_kernel(
    const float* __restrict__ h1, const int* __restrict__ csr,
    const int* __restrict__ offs, const int* __restrict__ cnt,
    const float* __restrict__ llw, const float* __restrict__ llb,
    const float* __restrict__ lrw, const float* __restrict__ c2llw,
    float* __restrict__ h2, float* __restrict__ t2) {
  __shared__ float wl[512], wr[512], w2c[512];
  __shared__ float bb[32];
  for (int idx = threadIdx.x; idx < 512; idx += 256) {
    wl[idx] = llw[idx];
    wr[idx] = lrw[idx];
    w2c[idx] = c2llw[idx];
  }
  if (threadIdx.x < 32) bb[threadIdx.x] = llb[threadIdx.x];
  __syncthreads();

  const int tid = blockIdx.x * 256 + threadIdx.x;
  const int i = tid >> 2;
  if (i >= N_NODES) return;
  const int t = threadIdx.x & 3;
  const int start = offs[i], deg = cnt[i];

  float4 acc = make_float4(0.f, 0.f, 0.f, 0.f);
  for (int e = 0; e < deg; ++e) {
    int s = csr[start + e];
    float4 a = *(const float4*)(h1 + (size_t)s * 16 + t * 4);
    acc.x += a.x; acc.y += a.y; acc.z += a.z; acc.w += a.w;
  }
  const float inv = 1.f / (float)(deg > 0 ? deg : 1);
  const float4 self = *(const float4*)(h1 + (size_t)i * 16 + t * 4);
  const float mk[4] = {acc.x * inv, acc.y * inv, acc.z * inv, acc.w * inv};
  const float sk[4] = {self.x, self.y, self.z, self.w};

  float4 p[8];
#pragma unroll
  for (int q = 0; q < 8; ++q) p[q] = make_float4(0.f, 0.f, 0.f, 0.f);
#pragma unroll
  for (int j = 0; j < 4; ++j) {
    const int k = 4 * t + j;
#pragma unroll
    for (int q = 0; q < 8; ++q) {
      float4 w4l = *(const float4*)&wl[k * 32 + 4 * q];
      float4 w4r = *(const float4*)&wr[k * 32 + 4 * q];
      p[q].x += mk[j] * w4l.x + sk[j] * w4r.x;
      p[q].y += mk[j] * w4l.y + sk[j] * w4r.y;
      p[q].z += mk[j] * w4l.z + sk[j] * w4r.z;
      p[q].w += mk[j] * w4l.w + sk[j] * w4r.w;
    }
  }
#pragma unroll
  for (int mask = 1; mask <= 2; mask <<= 1) {
#pragma unroll
    for (int q = 0; q < 8; ++q) {
      p[q].x += __shfl_xor(p[q].x, mask, 64);
      p[q].y += __shfl_xor(p[q].y, mask, 64);
      p[q].z += __shfl_xor(p[q].z, mask, 64);
      p[q].w += __shfl_xor(p[q].w, mask, 64);
    }
  }
  float o[32];
#pragma unroll
  for (int q = 0; q < 8; ++q) {
    o[4 * q + 0] = fmaxf(p[q].x + bb[4 * q + 0], 0.f);
    o[4 * q + 1] = fmaxf(p[q].y + bb[4 * q + 1], 0.f);
    o[4 * q + 2] = fmaxf(p[q].z + bb[4 * q + 2], 0.f);
    o[4 * q + 3] = fmaxf(p[q].w + bb[4 * q + 3], 0.f);
  }
  // lane t writes h2 quads 2t, 2t+1
#pragma unroll
  for (int m = 0; m < 2; ++m) {
    const int q = 2 * t + m;
    *(float4*)(h2 + (size_t)i * 32 + 4 * q) =
        make_float4(o[4 * q], o[4 * q + 1], o[4 * q + 2], o[4 * q + 3]);
  }
  // lane t computes t2 dims [4t..4t+3]
  float tt[4] = {0.f, 0.f, 0.f, 0.f};
#pragma unroll
  for (int k = 0; k < 32; ++k) {
    const float ok = o[k];
    const float4 wv = *(const float4*)&w2c[k * 16 + 4 * t];
    tt[0] += ok * wv.x; tt[1] += ok * wv.y;
    tt[2] += ok * wv.z; tt[3] += ok * wv.w;
  }
  *(float4*)(t2 + (size_t)i * 16 + 4 * t) =
      make_float4(tt[0], tt[1], tt[2], tt[3]);
}

// ---------------------------------------------------------------------------
// conv2 (pre-transformed, 16-dim agg) + fc2 + head -> d_out.
// 4 threads/node: gather t2[src] float4 slices; self term h2row @ lrw with
// k partitioned 8/lane; butterfly -> f[16]; lanes 0..2 emit head.
// ---------------------------------------------------------------------------
__global__ __launch_bounds__(256) void conv2_kernel(
    const float* __restrict__ t2, const float* __restrict__ h2,
    const int* __restrict__ csr, const int* __restrict__ offs,
    const int* __restrict__ cnt, const float* __restrict__ llb,
    const float* __restrict__ lrw, const float* __restrict__ fc2w,
    const float* __restrict__ fc2b, float* __restrict__ out) {
  __shared__ float wr[512];
  __shared__ float bb[16];
  __shared__ float w2[48];
  __shared__ float b2[3];
  for (int idx = threadIdx.x; idx < 512; idx += 256) wr[idx] = lrw[idx];
  if (threadIdx.x < 16) bb[threadIdx.x] = llb[threadIdx.x];
  else if (threadIdx.x >= 64 && threadIdx.x < 112) w2[threadIdx.x - 64] = fc2w[threadIdx.x - 64];
  else if (threadIdx.x >= 128 && threadIdx.x < 131) b2[threadIdx.x - 128] = fc2b[threadIdx.x - 128];
  __syncthreads();

  const int tid = blockIdx.x * 256 + threadIdx.x;
  const int i = tid >> 2;
  if (i >= N_NODES) return;
  const int t = threadIdx.x & 3;
  const int start = offs[i], deg = cnt[i];

  float4 acc = make_float4(0.f, 0.f, 0.f, 0.f);
  for (int e = 0; e < deg; ++e) {
    int s = csr[start + e];
    float4 a = *(const float4*)(t2 + (size_t)s * 16 + t * 4);
    acc.x += a.x; acc.y += a.y; acc.z += a.z; acc.w += a.w;
  }
  const float inv = 1.f / (float)(deg > 0 ? deg : 1);
  // P[16] partials: self-term over k in [8t..8t+7], plus owned mean dims.
  const float4 s0 = *(const float4*)(h2 + (size_t)i * 32 + 8 * t);
  const float4 s1 = *(const float4*)(h2 + (size_t)i * 32 + 8 * t + 4);
  const float sk[8] = {s0.x, s0.y, s0.z, s0.w, s1.x, s1.y, s1.z, s1.w};
  float4 p[4];
#pragma unroll
  for (int q = 0; q < 4; ++q) p[q] = make_float4(0.f, 0.f, 0.f, 0.f);
#pragma unroll
  for (int kk = 0; kk < 8; ++kk) {
    const int k = 8 * t + kk;
    const float s = sk[kk];
#pragma unroll
    for (int q = 0; q < 4; ++q) {
      const float4 wv = *(const float4*)&wr[k * 16 + 4 * q];
      p[q].x += s * wv.x; p[q].y += s * wv.y;
      p[q].z += s * wv.z; p[q].w += s * wv.w;
    }
  }
  // add owned mean dims [4t..4t+3]
  p[t].x += acc.x * inv; p[t].y += acc.y * inv;
  p[t].z += acc.z * inv; p[t].w += acc.w * inv;
#pragma unroll
  for (int mask = 1; mask <= 2; mask <<= 1) {
#pragma unroll
    for (int q = 0; q < 4; ++q) {
      p[q].x += __shfl_xor(p[q].x, mask, 64);
      p[q].y += __shfl_xor(p[q].y, mask, 64);
      p[q].z += __shfl_xor(p[q].z, mask, 64);
      p[q].w += __shfl_xor(p[q].w, mask, 64);
    }
  }
  if (t < 3) {
    float f[16];
#pragma unroll
    for (int q = 0; q < 4; ++q) {
      f[4 * q + 0] = fmaxf(p[q].x + bb[4 * q + 0], 0.f);
      f[4 * q + 1] = fmaxf(p[q].y + bb[4 * q + 1], 0.f);
      f[4 * q + 2] = fmaxf(p[q].z + bb[4 * q + 2], 0.f);
      f[4 * q + 3] = fmaxf(p[q].w + bb[4 * q + 3], 0.f);
    }
    float v0 = b2[0], v1 = b2[1], v2 = b2[2];
#pragma unroll
    for (int k = 0; k < 16; ++k) {
      v0 += f[k] * w2[k * 3 + 0];
      v1 += f[k] * w2[k * 3 + 1];
      v2 += f[k] * w2[k * 3 + 2];
    }
    float gsi = 1.f / (1.f + expf(-v1));
    float mxi = 1.f / (1.f + expf(-v2));
    float fsi = fmaxf(v0, 0.f) + gsi;
    float rv = (t == 0) ? fsi : ((t == 1) ? gsi : mxi);
    out[(size_t)i * 3 + t] = rv;
  }
}

extern "C" void kernel_launch(void* const* d_in, const int* in_sizes, int n_in,
                              void* d_out, int out_size, void* d_ws, size_t ws_size,
                              hipStream_t stream) {
  const float* x = (const float*)d_in[0];
  const int* ei = (const int*)d_in[1];
  const float* fc1w = (const float*)d_in[2];
  const float* fc1b = (const float*)d_in[3];
  const float* c1llw = (const float*)d_in[4];
  const float* c1llb = (const float*)d_in[5];
  const float* c1lrw = (const float*)d_in[6];
  const float* c2llw = (const float*)d_in[7];
  const float* c2llb = (const float*)d_in[8];
  const float* c2lrw = (const float*)d_in[9];
  const float* fc2w = (const float*)d_in[10];
  const float* fc2b = (const float*)d_in[11];
  float* outp = (float*)d_out;
  const int* src = ei;
  const int* dst = ei + N_EDGES;

  char* ws = (char*)d_ws;
  float* h1 = (float*)ws;    ws += (size_t)N_NODES * 16 * 4;
  float* h2 = (float*)ws;    ws += (size_t)N_NODES * 32 * 4;
  float* t2 = (float*)ws;    ws += (size_t)N_NODES * 16 * 4;
  int* staged = (int*)ws;    ws += (size_t)NB * CAP * 4;
  int* gcur = (int*)ws;      ws += (size_t)NB * 4;
  int* offs = (int*)ws;      ws += (size_t)N_NODES * 4;
  int* cnt = (int*)ws;       ws += (size_t)N_NODES * 4;
  (void)ws_size; (void)n_in; (void)in_sizes; (void)out_size;

  hipMemsetAsync(gcur, 0, (size_t)NB * 4, stream);
  fc1_kernel<<<512, 256, 0, stream>>>(x, fc1w, fc1b, h1);
  stage_kernel<<<512, 256, 0, stream>>>(src, dst, gcur, staged);
  finalize_kernel<<<NB, 256, 0, stream>>>(staged, gcur, offs, cnt);
  conv1_kernel<<<(N_NODES * 4 + 255) / 256, 256, 0, stream>>>(
      h1, staged, offs, cnt, c1llw, c1llb, c1lrw, c2llw, h2, t2);
  conv2_kernel<<<(N_NODES * 4 + 255) / 256, 256, 0, stream>>>(
      t2, h2, staged, offs, cnt, c2llb, c2lrw, fc2w, fc2b, outp);
}

// Round 5
// 293.375 us; speedup vs baseline: 2.8274x; 1.0388x over previous
//
#include <hip/hip_runtime.h>
#include <math.h>

#define N_NODES 100000
#define N_EDGES 3200000
#define BSHIFT 8
#define NPB 256                 // nodes per bucket = 1<<BSHIFT
#define BMASK (NPB - 1)
#define NB 391                  // ceil(N_NODES / NPB)
#define CAP 10240               // bucket capacity (mean 8192, +22 sigma)

// ---------------------------------------------------------------------------
// fc1: h1 = relu(x @ W1 + b1)   x:[N,512] f32, W1:[512,16], h1:[N,16]
// ---------------------------------------------------------------------------
__global__ __launch_bounds__(256) void fc1_kernel(
    const float* __restrict__ x, const float* __restrict__ w,
    const float* __restrict__ b, float* __restrict__ h1) {
  __shared__ float wt[16][512];
  for (int idx = threadIdx.x; idx < 512 * 16; idx += 256) {
    int e = idx >> 4, o = idx & 15;
    wt[o][e] = w[idx];
  }
  __syncthreads();

  const int lane = threadIdx.x & 63;
  const int wid = blockIdx.x * 4 + (threadIdx.x >> 6);
  const int waves_total = gridDim.x * 4;
  const float bl = b[lane & 15];
  const int ngroups = N_NODES / 4;  // 25000

  for (int g = wid; g < ngroups; g += waves_total) {
    const int r0 = g * 4;
    float4 xa[4][2];
#pragma unroll
    for (int r = 0; r < 4; ++r) {
      const float4* xp = (const float4*)(x + (size_t)(r0 + r) * 512 + lane * 4);
      xa[r][0] = xp[0];
      xa[r][1] = xp[64];
    }
    float acc[4][16];
#pragma unroll
    for (int r = 0; r < 4; ++r)
#pragma unroll
      for (int o = 0; o < 16; ++o) acc[r][o] = 0.f;

#pragma unroll
    for (int o = 0; o < 16; ++o) {
      const float4 w0 = *(const float4*)&wt[o][lane * 4];
      const float4 w1 = *(const float4*)&wt[o][256 + lane * 4];
#pragma unroll
      for (int r = 0; r < 4; ++r) {
        acc[r][o] += xa[r][0].x * w0.x + xa[r][0].y * w0.y +
                     xa[r][0].z * w0.z + xa[r][0].w * w0.w +
                     xa[r][1].x * w1.x + xa[r][1].y * w1.y +
                     xa[r][1].z * w1.z + xa[r][1].w * w1.w;
      }
    }

    const bool b0 = lane & 1, b1 = lane & 2, b2 = lane & 4, b3 = lane & 8;
#pragma unroll
    for (int r = 0; r < 4; ++r) {
      float v8[8];
#pragma unroll
      for (int j = 0; j < 8; ++j) {
        float keep = b0 ? acc[r][2 * j + 1] : acc[r][2 * j];
        float give = b0 ? acc[r][2 * j] : acc[r][2 * j + 1];
        v8[j] = keep + __shfl_xor(give, 1, 64);
      }
      float v4[4];
#pragma unroll
      for (int j = 0; j < 4; ++j) {
        float keep = b1 ? v8[2 * j + 1] : v8[2 * j];
        float give = b1 ? v8[2 * j] : v8[2 * j + 1];
        v4[j] = keep + __shfl_xor(give, 2, 64);
      }
      float v2[2];
#pragma unroll
      for (int j = 0; j < 2; ++j) {
        float keep = b2 ? v4[2 * j + 1] : v4[2 * j];
        float give = b2 ? v4[2 * j] : v4[2 * j + 1];
        v2[j] = keep + __shfl_xor(give, 4, 64);
      }
      float keep = b3 ? v2[1] : v2[0];
      float give = b3 ? v2[0] : v2[1];
      float v1 = keep + __shfl_xor(give, 8, 64);
      v1 += __shfl_xor(v1, 16, 64);
      v1 += __shfl_xor(v1, 32, 64);
      if (lane < 16) {
        h1[(size_t)(r0 + r) * 16 + lane] = fmaxf(v1 + bl, 0.f);
      }
    }
  }
}

// ---------------------------------------------------------------------------
// Bucket scatter: edges grouped by dst>>8, packed (src<<8)|dstlow.
// 256 blocks -> ~32-edge (128B, full line) runs per (block,bucket).
// ---------------------------------------------------------------------------
__global__ __launch_bounds__(256) void stage_kernel(
    const int* __restrict__ src, const int* __restrict__ dst,
    int* __restrict__ gcur, int* __restrict__ staged) {
  __shared__ int hist[NB];
  __shared__ int base[NB];
  const int tid = threadIdx.x;
  for (int i = tid; i < NB; i += 256) hist[i] = 0;
  __syncthreads();

  const int per = (N_EDGES + gridDim.x - 1) / gridDim.x;
  const int e0 = blockIdx.x * per;
  const int e1 = min(e0 + per, N_EDGES);

  for (int e = e0 + tid; e < e1; e += 256) {
    atomicAdd(&hist[dst[e] >> BSHIFT], 1);
  }
  __syncthreads();
  for (int bkt = tid; bkt < NB; bkt += 256) {
    int h = hist[bkt];
    base[bkt] = (h > 0) ? atomicAdd(&gcur[bkt], h) : 0;
    hist[bkt] = 0;  // reuse as local cursor
  }
  __syncthreads();
  for (int e = e0 + tid; e < e1; e += 256) {
    int d = dst[e];
    int s = src[e];
    int bkt = d >> BSHIFT;
    int pos = base[bkt] + atomicAdd(&hist[bkt], 1);
    if (pos < CAP) staged[bkt * CAP + pos] = (s << 8) | (d & BMASK);
  }
}

// ---------------------------------------------------------------------------
// finalize: per bucket, load staged slice into LDS, histogram local dst,
// block-scan -> per-node offs/cnt, scatter src back IN PLACE node-sorted.
// ---------------------------------------------------------------------------
__global__ __launch_bounds__(256) void finalize_kernel(
    int* __restrict__ staged, const int* __restrict__ gcur,
    int* __restrict__ offs, int* __restrict__ cnt) {
  __shared__ int ed[CAP];
  __shared__ int lcnt[NPB];
  __shared__ int lofs[NPB];
  __shared__ int sc[256];
  const int bkt = blockIdx.x, tid = threadIdx.x;
  const int nE = min(gcur[bkt], CAP);
  const int base = bkt * CAP;
  for (int e = tid; e < nE; e += 256) ed[e] = staged[base + e];
  lcnt[tid] = 0;
  __syncthreads();
  for (int e = tid; e < nE; e += 256) atomicAdd(&lcnt[ed[e] & BMASK], 1);
  __syncthreads();
  const int v = lcnt[tid];
  sc[tid] = v;
  __syncthreads();
  for (int d = 1; d < 256; d <<= 1) {
    int add = (tid >= d) ? sc[tid - d] : 0;
    __syncthreads();
    sc[tid] += add;
    __syncthreads();
  }
  const int excl = sc[tid] - v;
  lofs[tid] = excl;
  const int g = bkt * NPB + tid;
  if (g < N_NODES) {
    offs[g] = base + excl;
    cnt[g] = v;
  }
  lcnt[tid] = 0;  // reuse as cursor
  __syncthreads();
  for (int e = tid; e < nE; e += 256) {
    int u = ed[e];
    int dl = u & BMASK;
    int pos = lofs[dl] + atomicAdd(&lcnt[dl], 1);
    staged[base + pos] = u >> 8;  // plain src index, node-sorted
  }
}

// ---------------------------------------------------------------------------
// conv1 (16 -> 32): 8 threads/node = 2 groups x 4 lanes; groups take
// alternating edges, lane slice t covers dims [4t..4t+3]; one shfl_xor(4)
// merges groups, masks 1,2 complete the k-reduce. Epilogue: h2 quad per
// lane; t2 = o @ c2llw, 2 dims per lane.
// ---------------------------------------------------------------------------
__global__ __launch_bounds__(256) void conv1_kernel(
    const float* __restrict__ h1, const int* __restrict__ csr,
    const int* __restrict__ offs, const int* __restrict__ cnt,
    const float* __restrict__ llw, const float* __restrict__ llb,
    const float* __restrict__ lrw, const float* __restrict__ c2llw,
    float* __restrict__ h2, float* __restrict__ t2) {
  __shared__ float wl[512], wr[512], w2c[512];
  __shared__ float bb[32];
  for (int idx = threadIdx.x; idx < 512; idx += 256) {
    wl[idx] = llw[idx];
    wr[idx] = lrw[idx];
    w2c[idx] = c2llw[idx];
  }
  if (threadIdx.x < 32) bb[threadIdx.x] = llb[threadIdx.x];
  __syncthreads();

  const int tid = blockIdx.x * 256 + threadIdx.x;
  const int i = tid >> 3;
  if (i >= N_NODES) return;
  const int t8 = threadIdx.x & 7;
  const int gg = t8 >> 2;       // group 0/1
  const int t = t8 & 3;         // dim slice
  const int start = offs[i], deg = cnt[i];

  float4 acc = make_float4(0.f, 0.f, 0.f, 0.f);
  int e = gg;
  int snext = (e < deg) ? csr[start + e] : 0;
  for (; e < deg; e += 2) {
    const int s = snext;
    if (e + 2 < deg) snext = csr[start + e + 2];
    float4 a = *(const float4*)(h1 + (size_t)s * 16 + t * 4);
    acc.x += a.x; acc.y += a.y; acc.z += a.z; acc.w += a.w;
  }
  // merge the two groups
  acc.x += __shfl_xor(acc.x, 4, 64);
  acc.y += __shfl_xor(acc.y, 4, 64);
  acc.z += __shfl_xor(acc.z, 4, 64);
  acc.w += __shfl_xor(acc.w, 4, 64);

  const float inv = 1.f / (float)(deg > 0 ? deg : 1);
  const float4 self = *(const float4*)(h1 + (size_t)i * 16 + t * 4);
  const float mk[4] = {acc.x * inv, acc.y * inv, acc.z * inv, acc.w * inv};
  const float sk[4] = {self.x, self.y, self.z, self.w};

  float4 p[8];
#pragma unroll
  for (int q = 0; q < 8; ++q) p[q] = make_float4(0.f, 0.f, 0.f, 0.f);
#pragma unroll
  for (int j = 0; j < 4; ++j) {
    const int k = 4 * t + j;
#pragma unroll
    for (int q = 0; q < 8; ++q) {
      float4 w4l = *(const float4*)&wl[k * 32 + 4 * q];
      float4 w4r = *(const float4*)&wr[k * 32 + 4 * q];
      p[q].x += mk[j] * w4l.x + sk[j] * w4r.x;
      p[q].y += mk[j] * w4l.y + sk[j] * w4r.y;
      p[q].z += mk[j] * w4l.z + sk[j] * w4r.z;
      p[q].w += mk[j] * w4l.w + sk[j] * w4r.w;
    }
  }
#pragma unroll
  for (int mask = 1; mask <= 2; mask <<= 1) {
#pragma unroll
    for (int q = 0; q < 8; ++q) {
      p[q].x += __shfl_xor(p[q].x, mask, 64);
      p[q].y += __shfl_xor(p[q].y, mask, 64);
      p[q].z += __shfl_xor(p[q].z, mask, 64);
      p[q].w += __shfl_xor(p[q].w, mask, 64);
    }
  }
  float o[32];
#pragma unroll
  for (int q = 0; q < 8; ++q) {
    o[4 * q + 0] = fmaxf(p[q].x + bb[4 * q + 0], 0.f);
    o[4 * q + 1] = fmaxf(p[q].y + bb[4 * q + 1], 0.f);
    o[4 * q + 2] = fmaxf(p[q].z + bb[4 * q + 2], 0.f);
    o[4 * q + 3] = fmaxf(p[q].w + bb[4 * q + 3], 0.f);
  }
  // lane t8 writes h2 quad t8
  *(float4*)(h2 + (size_t)i * 32 + 4 * t8) =
      make_float4(o[4 * t8], o[4 * t8 + 1], o[4 * t8 + 2], o[4 * t8 + 3]);
  // lane t8 computes t2 dims [2*t8, 2*t8+1]
  float t0 = 0.f, t1 = 0.f;
#pragma unroll
  for (int k = 0; k < 32; ++k) {
    const float ok = o[k];
    t0 += ok * w2c[k * 16 + 2 * t8];
    t1 += ok * w2c[k * 16 + 2 * t8 + 1];
  }
  *(float2*)(t2 + (size_t)i * 16 + 2 * t8) = make_float2(t0, t1);
}

// ---------------------------------------------------------------------------
// conv2 (pre-transformed, 16-dim agg) + fc2 + head -> d_out.
// 8 threads/node: gather groups as conv1; self-term k-partition 4/lane;
// butterfly masks 1,2,4 -> f[16] everywhere; lanes 0..2 emit head.
// ---------------------------------------------------------------------------
__global__ __launch_bounds__(256) void conv2_kernel(
    const float* __restrict__ t2, const float* __restrict__ h2,
    const int* __restrict__ csr, const int* __restrict__ offs,
    const int* __restrict__ cnt, const float* __restrict__ llb,
    const float* __restrict__ lrw, const float* __restrict__ fc2w,
    const float* __restrict__ fc2b, float* __restrict__ out) {
  __shared__ float wr[512];
  __shared__ float bb[16];
  __shared__ float w2[48];
  __shared__ float b2[3];
  for (int idx = threadIdx.x; idx < 512; idx += 256) wr[idx] = lrw[idx];
  if (threadIdx.x < 16) bb[threadIdx.x] = llb[threadIdx.x];
  else if (threadIdx.x >= 64 && threadIdx.x < 112) w2[threadIdx.x - 64] = fc2w[threadIdx.x - 64];
  else if (threadIdx.x >= 128 && threadIdx.x < 131) b2[threadIdx.x - 128] = fc2b[threadIdx.x - 128];
  __syncthreads();

  const int tid = blockIdx.x * 256 + threadIdx.x;
  const int i = tid >> 3;
  if (i >= N_NODES) return;
  const int t8 = threadIdx.x & 7;
  const int gg = t8 >> 2;
  const int t = t8 & 3;
  const int start = offs[i], deg = cnt[i];

  float4 acc = make_float4(0.f, 0.f, 0.f, 0.f);
  int e = gg;
  int snext = (e < deg) ? csr[start + e] : 0;
  for (; e < deg; e += 2) {
    const int s = snext;
    if (e + 2 < deg) snext = csr[start + e + 2];
    float4 a = *(const float4*)(t2 + (size_t)s * 16 + t * 4);
    acc.x += a.x; acc.y += a.y; acc.z += a.z; acc.w += a.w;
  }
  acc.x += __shfl_xor(acc.x, 4, 64);
  acc.y += __shfl_xor(acc.y, 4, 64);
  acc.z += __shfl_xor(acc.z, 4, 64);
  acc.w += __shfl_xor(acc.w, 4, 64);

  const float inv = 1.f / (float)(deg > 0 ? deg : 1);
  // self-term: k in [4*t8 .. 4*t8+3]
  const float4 s0 = *(const float4*)(h2 + (size_t)i * 32 + 4 * t8);
  const float sk[4] = {s0.x, s0.y, s0.z, s0.w};
  float4 p[4];
#pragma unroll
  for (int q = 0; q < 4; ++q) p[q] = make_float4(0.f, 0.f, 0.f, 0.f);
#pragma unroll
  for (int kk = 0; kk < 4; ++kk) {
    const int k = 4 * t8 + kk;
    const float s = sk[kk];
#pragma unroll
    for (int q = 0; q < 4; ++q) {
      const float4 wv = *(const float4*)&wr[k * 16 + 4 * q];
      p[q].x += s * wv.x; p[q].y += s * wv.y;
      p[q].z += s * wv.z; p[q].w += s * wv.w;
    }
  }
  // add owned mean dims [4t..4t+3] from group 0 only (acc is group-merged)
  if (gg == 0) {
    p[t].x += acc.x * inv; p[t].y += acc.y * inv;
    p[t].z += acc.z * inv; p[t].w += acc.w * inv;
  }
#pragma unroll
  for (int mask = 1; mask <= 4; mask <<= 1) {
#pragma unroll
    for (int q = 0; q < 4; ++q) {
      p[q].x += __shfl_xor(p[q].x, mask, 64);
      p[q].y += __shfl_xor(p[q].y, mask, 64);
      p[q].z += __shfl_xor(p[q].z, mask, 64);
      p[q].w += __shfl_xor(p[q].w, mask, 64);
    }
  }
  if (t8 < 3) {
    float f[16];
#pragma unroll
    for (int q = 0; q < 4; ++q) {
      f[4 * q + 0] = fmaxf(p[q].x + bb[4 * q + 0], 0.f);
      f[4 * q + 1] = fmaxf(p[q].y + bb[4 * q + 1], 0.f);
      f[4 * q + 2] = fmaxf(p[q].z + bb[4 * q + 2], 0.f);
      f[4 * q + 3] = fmaxf(p[q].w + bb[4 * q + 3], 0.f);
    }
    float v0 = b2[0], v1 = b2[1], v2 = b2[2];
#pragma unroll
    for (int k = 0; k < 16; ++k) {
      v0 += f[k] * w2[k * 3 + 0];
      v1 += f[k] * w2[k * 3 + 1];
      v2 += f[k] * w2[k * 3 + 2];
    }
    float gsi = 1.f / (1.f + expf(-v1));
    float mxi = 1.f / (1.f + expf(-v2));
    float fsi = fmaxf(v0, 0.f) + gsi;
    float rv = (t8 == 0) ? fsi : ((t8 == 1) ? gsi : mxi);
    out[(size_t)i * 3 + t8] = rv;
  }
}

extern "C" void kernel_launch(void* const* d_in, const int* in_sizes, int n_in,
                              void* d_out, int out_size, void* d_ws, size_t ws_size,
                              hipStream_t stream) {
  const float* x = (const float*)d_in[0];
  const int* ei = (const int*)d_in[1];
  const float* fc1w = (const float*)d_in[2];
  const float* fc1b = (const float*)d_in[3];
  const float* c1llw = (const float*)d_in[4];
  const float* c1llb = (const float*)d_in[5];
  const float* c1lrw = (const float*)d_in[6];
  const float* c2llw = (const float*)d_in[7];
  const float* c2llb = (const float*)d_in[8];
  const float* c2lrw = (const float*)d_in[9];
  const float* fc2w = (const float*)d_in[10];
  const float* fc2b = (const float*)d_in[11];
  float* outp = (float*)d_out;
  const int* src = ei;
  const int* dst = ei + N_EDGES;

  char* ws = (char*)d_ws;
  float* h1 = (float*)ws;    ws += (size_t)N_NODES * 16 * 4;
  float* h2 = (float*)ws;    ws += (size_t)N_NODES * 32 * 4;
  float* t2 = (float*)ws;    ws += (size_t)N_NODES * 16 * 4;
  int* staged = (int*)ws;    ws += (size_t)NB * CAP * 4;
  int* gcur = (int*)ws;      ws += (size_t)NB * 4;
  int* offs = (int*)ws;      ws += (size_t)N_NODES * 4;
  int* cnt = (int*)ws;       ws += (size_t)N_NODES * 4;
  (void)ws_size; (void)n_in; (void)in_sizes; (void)out_size;

  hipMemsetAsync(gcur, 0, (size_t)NB * 4, stream);
  fc1_kernel<<<512, 256, 0, stream>>>(x, fc1w, fc1b, h1);
  stage_kernel<<<256, 256, 0, stream>>>(src, dst, gcur, staged);
  finalize_kernel<<<NB, 256, 0, stream>>>(staged, gcur, offs, cnt);
  conv1_kernel<<<(N_NODES * 8 + 255) / 256, 256, 0, stream>>>(
      h1, staged, offs, cnt, c1llw, c1llb, c1lrw, c2llw, h2, t2);
  conv2_kernel<<<(N_NODES * 8 + 255) / 256, 256, 0, stream>>>(
      t2, h2, staged, offs, cnt, c2llb, c2lrw, fc2w, fc2b, outp);
}

// Round 6
// 292.907 us; speedup vs baseline: 2.8319x; 1.0016x over previous
//
#include <hip/hip_runtime.h>
#include <math.h>

#define N_NODES 100000
#define N_EDGES 3200000
#define BSHIFT 8
#define NPB 256                 // nodes per bucket = 1<<BSHIFT
#define BMASK (NPB - 1)
#define NB 391                  // ceil(N_NODES / NPB)
#define CAP 10240               // bucket capacity (mean 8192, +22 sigma)
#define FC1_BLOCKS 512
#define STG_BLOCKS 256

// ---------------------------------------------------------------------------
// Fused fc1 ∥ stage. Blocks [0,512): h1 = relu(x@W1+b1). Blocks [512,768):
// bucket-scatter edges by dst>>8, packed (src<<8)|dstlow. The two halves
// touch disjoint data; fusing overlaps HBM-bound fc1 with the atomic-bound
// scatter instead of serializing them.
// ---------------------------------------------------------------------------
__global__ __launch_bounds__(256) void fc1_stage_kernel(
    const float* __restrict__ x, const float* __restrict__ w,
    const float* __restrict__ b, float* __restrict__ h1,
    const int* __restrict__ src, const int* __restrict__ dst,
    int* __restrict__ gcur, int* __restrict__ staged) {
  __shared__ float wt[16][512];          // fc1 half
  __shared__ int hist[NB], base[NB];     // stage half

  if (blockIdx.x < FC1_BLOCKS) {
    // ---------------- fc1 ----------------
    for (int idx = threadIdx.x; idx < 512 * 16; idx += 256) {
      int e = idx >> 4, o = idx & 15;
      wt[o][e] = w[idx];
    }
    __syncthreads();

    const int lane = threadIdx.x & 63;
    const int wid = blockIdx.x * 4 + (threadIdx.x >> 6);
    const int waves_total = FC1_BLOCKS * 4;
    const float bl = b[lane & 15];
    const int ngroups = N_NODES / 4;  // 25000

    for (int g = wid; g < ngroups; g += waves_total) {
      const int r0 = g * 4;
      float4 xa[4][2];
#pragma unroll
      for (int r = 0; r < 4; ++r) {
        const float4* xp = (const float4*)(x + (size_t)(r0 + r) * 512 + lane * 4);
        xa[r][0] = xp[0];
        xa[r][1] = xp[64];
      }
      float acc[4][16];
#pragma unroll
      for (int r = 0; r < 4; ++r)
#pragma unroll
        for (int o = 0; o < 16; ++o) acc[r][o] = 0.f;

#pragma unroll
      for (int o = 0; o < 16; ++o) {
        const float4 w0 = *(const float4*)&wt[o][lane * 4];
        const float4 w1 = *(const float4*)&wt[o][256 + lane * 4];
#pragma unroll
        for (int r = 0; r < 4; ++r) {
          acc[r][o] += xa[r][0].x * w0.x + xa[r][0].y * w0.y +
                       xa[r][0].z * w0.z + xa[r][0].w * w0.w +
                       xa[r][1].x * w1.x + xa[r][1].y * w1.y +
                       xa[r][1].z * w1.z + xa[r][1].w * w1.w;
        }
      }

      const bool b0 = lane & 1, b1 = lane & 2, b2 = lane & 4, b3 = lane & 8;
#pragma unroll
      for (int r = 0; r < 4; ++r) {
        float v8[8];
#pragma unroll
        for (int j = 0; j < 8; ++j) {
          float keep = b0 ? acc[r][2 * j + 1] : acc[r][2 * j];
          float give = b0 ? acc[r][2 * j] : acc[r][2 * j + 1];
          v8[j] = keep + __shfl_xor(give, 1, 64);
        }
        float v4[4];
#pragma unroll
        for (int j = 0; j < 4; ++j) {
          float keep = b1 ? v8[2 * j + 1] : v8[2 * j];
          float give = b1 ? v8[2 * j] : v8[2 * j + 1];
          v4[j] = keep + __shfl_xor(give, 2, 64);
        }
        float v2[2];
#pragma unroll
        for (int j = 0; j < 2; ++j) {
          float keep = b2 ? v4[2 * j + 1] : v4[2 * j];
          float give = b2 ? v4[2 * j] : v4[2 * j + 1];
          v2[j] = keep + __shfl_xor(give, 4, 64);
        }
        float keep = b3 ? v2[1] : v2[0];
        float give = b3 ? v2[0] : v2[1];
        float v1 = keep + __shfl_xor(give, 8, 64);
        v1 += __shfl_xor(v1, 16, 64);
        v1 += __shfl_xor(v1, 32, 64);
        if (lane < 16) {
          h1[(size_t)(r0 + r) * 16 + lane] = fmaxf(v1 + bl, 0.f);
        }
      }
    }
  } else {
    // ---------------- stage ----------------
    const int tid = threadIdx.x;
    for (int i = tid; i < NB; i += 256) hist[i] = 0;
    __syncthreads();

    const int sb = blockIdx.x - FC1_BLOCKS;
    const int per = (N_EDGES + STG_BLOCKS - 1) / STG_BLOCKS;
    const int e0 = sb * per;
    const int e1 = min(e0 + per, N_EDGES);

    for (int e = e0 + tid; e < e1; e += 256) {
      atomicAdd(&hist[dst[e] >> BSHIFT], 1);
    }
    __syncthreads();
    for (int bkt = tid; bkt < NB; bkt += 256) {
      int h = hist[bkt];
      base[bkt] = (h > 0) ? atomicAdd(&gcur[bkt], h) : 0;
      hist[bkt] = 0;  // reuse as local cursor
    }
    __syncthreads();
    for (int e = e0 + tid; e < e1; e += 256) {
      int d = dst[e];
      int s = src[e];
      int bkt = d >> BSHIFT;
      int pos = base[bkt] + atomicAdd(&hist[bkt], 1);
      if (pos < CAP) staged[bkt * CAP + pos] = (s << 8) | (d & BMASK);
    }
  }
}

// ---------------------------------------------------------------------------
// finalize: per bucket, load staged slice into LDS, histogram local dst,
// block-scan -> per-node offs/cnt, scatter src back IN PLACE node-sorted.
// ---------------------------------------------------------------------------
__global__ __launch_bounds__(256) void finalize_kernel(
    int* __restrict__ staged, const int* __restrict__ gcur,
    int* __restrict__ offs, int* __restrict__ cnt) {
  __shared__ int ed[CAP];
  __shared__ int lcnt[NPB];
  __shared__ int lofs[NPB];
  __shared__ int sc[256];
  const int bkt = blockIdx.x, tid = threadIdx.x;
  const int nE = min(gcur[bkt], CAP);
  const int base = bkt * CAP;
  for (int e = tid; e < nE; e += 256) ed[e] = staged[base + e];
  lcnt[tid] = 0;
  __syncthreads();
  for (int e = tid; e < nE; e += 256) atomicAdd(&lcnt[ed[e] & BMASK], 1);
  __syncthreads();
  const int v = lcnt[tid];
  sc[tid] = v;
  __syncthreads();
  for (int d = 1; d < 256; d <<= 1) {
    int add = (tid >= d) ? sc[tid - d] : 0;
    __syncthreads();
    sc[tid] += add;
    __syncthreads();
  }
  const int excl = sc[tid] - v;
  lofs[tid] = excl;
  const int g = bkt * NPB + tid;
  if (g < N_NODES) {
    offs[g] = base + excl;
    cnt[g] = v;
  }
  lcnt[tid] = 0;  // reuse as cursor
  __syncthreads();
  for (int e = tid; e < nE; e += 256) {
    int u = ed[e];
    int dl = u & BMASK;
    int pos = lofs[dl] + atomicAdd(&lcnt[dl], 1);
    staged[base + pos] = u >> 8;  // plain src index, node-sorted
  }
}

// ---------------------------------------------------------------------------
// conv1 (16 -> 32): 8 threads/node = 2 groups x 4 lanes; groups take
// alternating edges, lane slice t covers dims [4t..4t+3]; shfl_xor(4)
// merges groups, masks 1,2 complete the k-reduce. Epilogue: h2 quad per
// lane; t2 = o @ c2llw, 2 dims per lane.
// ---------------------------------------------------------------------------
__global__ __launch_bounds__(256) void conv1_kernel(
    const float* __restrict__ h1, const int* __restrict__ csr,
    const int* __restrict__ offs, const int* __restrict__ cnt,
    const float* __restrict__ llw, const float* __restrict__ llb,
    const float* __restrict__ lrw, const float* __restrict__ c2llw,
    float* __restrict__ h2, float* __restrict__ t2) {
  __shared__ float wl[512], wr[512], w2c[512];
  __shared__ float bb[32];
  for (int idx = threadIdx.x; idx < 512; idx += 256) {
    wl[idx] = llw[idx];
    wr[idx] = lrw[idx];
    w2c[idx] = c2llw[idx];
  }
  if (threadIdx.x < 32) bb[threadIdx.x] = llb[threadIdx.x];
  __syncthreads();

  const int tid = blockIdx.x * 256 + threadIdx.x;
  const int i = tid >> 3;
  if (i >= N_NODES) return;
  const int t8 = threadIdx.x & 7;
  const int gg = t8 >> 2;       // group 0/1
  const int t = t8 & 3;         // dim slice
  const int start = offs[i], deg = cnt[i];

  float4 acc = make_float4(0.f, 0.f, 0.f, 0.f);
  int e = gg;
  int snext = (e < deg) ? csr[start + e] : 0;
  for (; e < deg; e += 2) {
    const int s = snext;
    if (e + 2 < deg) snext = csr[start + e + 2];
    float4 a = *(const float4*)(h1 + (size_t)s * 16 + t * 4);
    acc.x += a.x; acc.y += a.y; acc.z += a.z; acc.w += a.w;
  }
  acc.x += __shfl_xor(acc.x, 4, 64);
  acc.y += __shfl_xor(acc.y, 4, 64);
  acc.z += __shfl_xor(acc.z, 4, 64);
  acc.w += __shfl_xor(acc.w, 4, 64);

  const float inv = 1.f / (float)(deg > 0 ? deg : 1);
  const float4 self = *(const float4*)(h1 + (size_t)i * 16 + t * 4);
  const float mk[4] = {acc.x * inv, acc.y * inv, acc.z * inv, acc.w * inv};
  const float sk[4] = {self.x, self.y, self.z, self.w};

  float4 p[8];
#pragma unroll
  for (int q = 0; q < 8; ++q) p[q] = make_float4(0.f, 0.f, 0.f, 0.f);
#pragma unroll
  for (int j = 0; j < 4; ++j) {
    const int k = 4 * t + j;
#pragma unroll
    for (int q = 0; q < 8; ++q) {
      float4 w4l = *(const float4*)&wl[k * 32 + 4 * q];
      float4 w4r = *(const float4*)&wr[k * 32 + 4 * q];
      p[q].x += mk[j] * w4l.x + sk[j] * w4r.x;
      p[q].y += mk[j] * w4l.y + sk[j] * w4r.y;
      p[q].z += mk[j] * w4l.z + sk[j] * w4r.z;
      p[q].w += mk[j] * w4l.w + sk[j] * w4r.w;
    }
  }
#pragma unroll
  for (int mask = 1; mask <= 2; mask <<= 1) {
#pragma unroll
    for (int q = 0; q < 8; ++q) {
      p[q].x += __shfl_xor(p[q].x, mask, 64);
      p[q].y += __shfl_xor(p[q].y, mask, 64);
      p[q].z += __shfl_xor(p[q].z, mask, 64);
      p[q].w += __shfl_xor(p[q].w, mask, 64);
    }
  }
  float o[32];
#pragma unroll
  for (int q = 0; q < 8; ++q) {
    o[4 * q + 0] = fmaxf(p[q].x + bb[4 * q + 0], 0.f);
    o[4 * q + 1] = fmaxf(p[q].y + bb[4 * q + 1], 0.f);
    o[4 * q + 2] = fmaxf(p[q].z + bb[4 * q + 2], 0.f);
    o[4 * q + 3] = fmaxf(p[q].w + bb[4 * q + 3], 0.f);
  }
  *(float4*)(h2 + (size_t)i * 32 + 4 * t8) =
      make_float4(o[4 * t8], o[4 * t8 + 1], o[4 * t8 + 2], o[4 * t8 + 3]);
  float t0 = 0.f, t1 = 0.f;
#pragma unroll
  for (int k = 0; k < 32; ++k) {
    const float ok = o[k];
    t0 += ok * w2c[k * 16 + 2 * t8];
    t1 += ok * w2c[k * 16 + 2 * t8 + 1];
  }
  *(float2*)(t2 + (size_t)i * 16 + 2 * t8) = make_float2(t0, t1);
}

// ---------------------------------------------------------------------------
// conv2 (pre-transformed, 16-dim agg) + fc2 + head -> d_out.
// 8 threads/node; butterfly masks 1,2,4 -> f[16]; lanes 0..2 emit head.
// ---------------------------------------------------------------------------
__global__ __launch_bounds__(256) void conv2_kernel(
    const float* __restrict__ t2, const float* __restrict__ h2,
    const int* __restrict__ csr, const int* __restrict__ offs,
    const int* __restrict__ cnt, const float* __restrict__ llb,
    const float* __restrict__ lrw, const float* __restrict__ fc2w,
    const float* __restrict__ fc2b, float* __restrict__ out) {
  __shared__ float wr[512];
  __shared__ float bb[16];
  __shared__ float w2[48];
  __shared__ float b2[3];
  for (int idx = threadIdx.x; idx < 512; idx += 256) wr[idx] = lrw[idx];
  if (threadIdx.x < 16) bb[threadIdx.x] = llb[threadIdx.x];
  else if (threadIdx.x >= 64 && threadIdx.x < 112) w2[threadIdx.x - 64] = fc2w[threadIdx.x - 64];
  else if (threadIdx.x >= 128 && threadIdx.x < 131) b2[threadIdx.x - 128] = fc2b[threadIdx.x - 128];
  __syncthreads();

  const int tid = blockIdx.x * 256 + threadIdx.x;
  const int i = tid >> 3;
  if (i >= N_NODES) return;
  const int t8 = threadIdx.x & 7;
  const int gg = t8 >> 2;
  const int t = t8 & 3;
  const int start = offs[i], deg = cnt[i];

  float4 acc = make_float4(0.f, 0.f, 0.f, 0.f);
  int e = gg;
  int snext = (e < deg) ? csr[start + e] : 0;
  for (; e < deg; e += 2) {
    const int s = snext;
    if (e + 2 < deg) snext = csr[start + e + 2];
    float4 a = *(const float4*)(t2 + (size_t)s * 16 + t * 4);
    acc.x += a.x; acc.y += a.y; acc.z += a.z; acc.w += a.w;
  }
  acc.x += __shfl_xor(acc.x, 4, 64);
  acc.y += __shfl_xor(acc.y, 4, 64);
  acc.z += __shfl_xor(acc.z, 4, 64);
  acc.w += __shfl_xor(acc.w, 4, 64);

  const float inv = 1.f / (float)(deg > 0 ? deg : 1);
  const float4 s0 = *(const float4*)(h2 + (size_t)i * 32 + 4 * t8);
  const float sk[4] = {s0.x, s0.y, s0.z, s0.w};
  float4 p[4];
#pragma unroll
  for (int q = 0; q < 4; ++q) p[q] = make_float4(0.f, 0.f, 0.f, 0.f);
#pragma unroll
  for (int kk = 0; kk < 4; ++kk) {
    const int k = 4 * t8 + kk;
    const float s = sk[kk];
#pragma unroll
    for (int q = 0; q < 4; ++q) {
      const float4 wv = *(const float4*)&wr[k * 16 + 4 * q];
      p[q].x += s * wv.x; p[q].y += s * wv.y;
      p[q].z += s * wv.z; p[q].w += s * wv.w;
    }
  }
  if (gg == 0) {
    p[t].x += acc.x * inv; p[t].y += acc.y * inv;
    p[t].z += acc.z * inv; p[t].w += acc.w * inv;
  }
#pragma unroll
  for (int mask = 1; mask <= 4; mask <<= 1) {
#pragma unroll
    for (int q = 0; q < 4; ++q) {
      p[q].x += __shfl_xor(p[q].x, mask, 64);
      p[q].y += __shfl_xor(p[q].y, mask, 64);
      p[q].z += __shfl_xor(p[q].z, mask, 64);
      p[q].w += __shfl_xor(p[q].w, mask, 64);
    }
  }
  if (t8 < 3) {
    float f[16];
#pragma unroll
    for (int q = 0; q < 4; ++q) {
      f[4 * q + 0] = fmaxf(p[q].x + bb[4 * q + 0], 0.f);
      f[4 * q + 1] = fmaxf(p[q].y + bb[4 * q + 1], 0.f);
      f[4 * q + 2] = fmaxf(p[q].z + bb[4 * q + 2], 0.f);
      f[4 * q + 3] = fmaxf(p[q].w + bb[4 * q + 3], 0.f);
    }
    float v0 = b2[0], v1 = b2[1], v2 = b2[2];
#pragma unroll
    for (int k = 0; k < 16; ++k) {
      v0 += f[k] * w2[k * 3 + 0];
      v1 += f[k] * w2[k * 3 + 1];
      v2 += f[k] * w2[k * 3 + 2];
    }
    float gsi = 1.f / (1.f + expf(-v1));
    float mxi = 1.f / (1.f + expf(-v2));
    float fsi = fmaxf(v0, 0.f) + gsi;
    float rv = (t8 == 0) ? fsi : ((t8 == 1) ? gsi : mxi);
    out[(size_t)i * 3 + t8] = rv;
  }
}

extern "C" void kernel_launch(void* const* d_in, const int* in_sizes, int n_in,
                              void* d_out, int out_size, void* d_ws, size_t ws_size,
                              hipStream_t stream) {
  const float* x = (const float*)d_in[0];
  const int* ei = (const int*)d_in[1];
  const float* fc1w = (const float*)d_in[2];
  const float* fc1b = (const float*)d_in[3];
  const float* c1llw = (const float*)d_in[4];
  const float* c1llb = (const float*)d_in[5];
  const float* c1lrw = (const float*)d_in[6];
  const float* c2llw = (const float*)d_in[7];
  const float* c2llb = (const float*)d_in[8];
  const float* c2lrw = (const float*)d_in[9];
  const float* fc2w = (const float*)d_in[10];
  const float* fc2b = (const float*)d_in[11];
  float* outp = (float*)d_out;
  const int* src = ei;
  const int* dst = ei + N_EDGES;

  char* ws = (char*)d_ws;
  float* h1 = (float*)ws;    ws += (size_t)N_NODES * 16 * 4;
  float* h2 = (float*)ws;    ws += (size_t)N_NODES * 32 * 4;
  float* t2 = (float*)ws;    ws += (size_t)N_NODES * 16 * 4;
  int* staged = (int*)ws;    ws += (size_t)NB * CAP * 4;
  int* gcur = (int*)ws;      ws += (size_t)NB * 4;
  int* offs = (int*)ws;      ws += (size_t)N_NODES * 4;
  int* cnt = (int*)ws;       ws += (size_t)N_NODES * 4;
  (void)ws_size; (void)n_in; (void)in_sizes; (void)out_size;

  hipMemsetAsync(gcur, 0, (size_t)NB * 4, stream);
  fc1_stage_kernel<<<FC1_BLOCKS + STG_BLOCKS, 256, 0, stream>>>(
      x, fc1w, fc1b, h1, src, dst, gcur, staged);
  finalize_kernel<<<NB, 256, 0, stream>>>(staged, gcur, offs, cnt);
  conv1_kernel<<<(N_NODES * 8 + 255) / 256, 256, 0, stream>>>(
      h1, staged, offs, cnt, c1llw, c1llb, c1lrw, c2llw, h2, t2);
  conv2_kernel<<<(N_NODES * 8 + 255) / 256, 256, 0, stream>>>(
      t2, h2, staged, offs, cnt, c2llb, c2lrw, fc2w, fc2b, outp);
}